// Round 1
// baseline (181.392 us; speedup 1.0000x reference)
//
#include <hip/hip_runtime.h>
#include <hip/hip_bf16.h>

#define B_ROWS 32768

typedef unsigned short u16;
typedef unsigned int u32;
typedef float f32x4 __attribute__((ext_vector_type(4)));
typedef __bf16 bf16x8 __attribute__((ext_vector_type(8)));

__device__ __forceinline__ u16 f2bf(float f){
    union { float f; u32 u; } v; v.f = f;
    return (u16)((v.u + 0x7FFFu + ((v.u >> 16) & 1u)) >> 16);
}
__device__ __forceinline__ float bf2f(u16 h){
    union { u32 u; float f; } v; v.u = ((u32)h) << 16; return v.f;
}
__device__ __forceinline__ u32 pack2(float a, float b){
    return (u32)f2bf(a) | ((u32)f2bf(b) << 16);
}

// ---------------- weight cast + transpose to [out_col][k] bf16 ----------------
__global__ void cast_weights_kernel(const float* __restrict__ proj_w,
                                    const float* __restrict__ exp_w1,
                                    const float* __restrict__ exp_w2,
                                    const float* __restrict__ pre_w,
                                    u16* __restrict__ pwT, u16* __restrict__ w1T,
                                    u16* __restrict__ w2T, u16* __restrict__ prwT){
    int i = blockIdx.x * 256 + threadIdx.x;
    if (i < 294912){                       // proj_wT [3][128][768]
        int m = i / 98304, r = i % 98304;
        int p = r / 768, d = r % 768;
        pwT[i] = f2bf(proj_w[m*98304 + d*128 + p]);
    } else if (i < 688128){                // exp_w1T [8][128][384]
        int j = i - 294912;
        int e = j / 49152, r = j % 49152;
        int h = r / 384, k = r % 384;
        w1T[j] = f2bf(exp_w1[e*49152 + k*128 + h]);
    } else if (i < 819200){                // exp_w2T [8][128][128]
        int j = i - 688128;
        int e = j / 16384, r = j % 16384;
        int o = r / 128, k = r % 128;
        w2T[j] = f2bf(exp_w2[e*16384 + k*128 + o]);
    } else if (i < 827392){                // pre_wT [64][128]
        int j = i - 819200;
        int o = j / 128, k = j % 128;
        prwT[j] = f2bf(pre_w[k*64 + o]);
    }
}

// ---------------- proj: x[b, m*128+p] = feat_m[b,:] @ proj_w[m] + proj_b ------
// grid (B/128, 3), 256 threads = 4 waves (2x2), tile 128x128, BK=32
__global__ __launch_bounds__(256) void proj_kernel(
    const float* __restrict__ ft, const float* __restrict__ fa, const float* __restrict__ fv,
    const u16* __restrict__ pwT, const float* __restrict__ proj_b,
    u16* __restrict__ xq)
{
    __shared__ u16 As[128][40];   // +8 pad: rows stay 16B aligned, 2-way max bank alias
    __shared__ u16 Bs[128][40];
    const int m = blockIdx.y;
    const float* feat = (m == 0) ? ft : (m == 1) ? fa : fv;
    const int row0 = blockIdx.x * 128;
    const int tid  = threadIdx.x;
    const int lane = tid & 63, wid = tid >> 6;
    const int wr = wid >> 1, wc = wid & 1;
    const int lr = lane & 15, lk8 = (lane >> 4) * 8, r4 = (lane >> 4) * 4;

    f32x4 acc[4][4];
    #pragma unroll
    for (int i = 0; i < 4; i++)
        #pragma unroll
        for (int j = 0; j < 4; j++) acc[i][j] = {0.f, 0.f, 0.f, 0.f};

    const int srow = tid >> 1, sh = (tid & 1) * 16;
    const float* aG = feat + (size_t)(row0 + srow) * 768 + sh;
    const u16*   bG = pwT + (size_t)m * 98304 + (size_t)srow * 768 + sh;

    for (int kt = 0; kt < 768; kt += 32){
        __syncthreads();
        float4 f0 = *(const float4*)(aG + kt);
        float4 f1 = *(const float4*)(aG + kt + 4);
        float4 f2 = *(const float4*)(aG + kt + 8);
        float4 f3 = *(const float4*)(aG + kt + 12);
        uint4 b0 = *(const uint4*)(bG + kt);
        uint4 b1 = *(const uint4*)(bG + kt + 8);
        uint4 pa0 = {pack2(f0.x,f0.y), pack2(f0.z,f0.w), pack2(f1.x,f1.y), pack2(f1.z,f1.w)};
        uint4 pa1 = {pack2(f2.x,f2.y), pack2(f2.z,f2.w), pack2(f3.x,f3.y), pack2(f3.z,f3.w)};
        *(uint4*)&As[srow][sh]     = pa0;
        *(uint4*)&As[srow][sh + 8] = pa1;
        *(uint4*)&Bs[srow][sh]     = b0;
        *(uint4*)&Bs[srow][sh + 8] = b1;
        __syncthreads();
        bf16x8 af[4], bfr[4];
        #pragma unroll
        for (int mi = 0; mi < 4; mi++) af[mi]  = *(const bf16x8*)&As[wr*64 + mi*16 + lr][lk8];
        #pragma unroll
        for (int ni = 0; ni < 4; ni++) bfr[ni] = *(const bf16x8*)&Bs[wc*64 + ni*16 + lr][lk8];
        #pragma unroll
        for (int mi = 0; mi < 4; mi++)
            #pragma unroll
            for (int ni = 0; ni < 4; ni++)
                acc[mi][ni] = __builtin_amdgcn_mfma_f32_16x16x32_bf16(af[mi], bfr[ni], acc[mi][ni], 0, 0, 0);
    }
    #pragma unroll
    for (int mi = 0; mi < 4; mi++){
        #pragma unroll
        for (int ni = 0; ni < 4; ni++){
            int col = wc*64 + ni*16 + lr;
            float bias = proj_b[m*128 + col];
            #pragma unroll
            for (int j = 0; j < 4; j++){
                int row = row0 + wr*64 + mi*16 + r4 + j;
                xq[(size_t)row*384 + m*128 + col] = f2bf(acc[mi][ni][j] + bias);
            }
        }
    }
}

// ---------------- fused gate + experts + pre + head ---------------------------
// grid (B/64), 256 threads = 4 waves (2x2). LDS ~78KB -> 2 blocks/CU.
__global__ __launch_bounds__(256) void moe_kernel(
    const u16* __restrict__ xq,
    const u16* __restrict__ w1T, const u16* __restrict__ w2T, const u16* __restrict__ prwT,
    const float* __restrict__ gate_w, const float* __restrict__ gate_b,
    const float* __restrict__ exp_b1, const float* __restrict__ exp_b2,
    const float* __restrict__ pre_b, const float* __restrict__ head_w, const float* __restrict__ head_b,
    float* __restrict__ out)
{
    __shared__ u16  Xs[64][392];   // x tile, full K=384 (+8 pad)
    __shared__ u16  Ws[128][40];   // per-K-step weight staging
    __shared__ u16  Hs[64][136];   // h tile / fused tile (+8 pad)
    __shared__ float GW[64][8];    // gate weights

    const int row0 = blockIdx.x * 64;
    const int tid  = threadIdx.x;
    const int lane = tid & 63, wid = tid >> 6;
    const int wr = wid >> 1, wc = wid & 1;
    const int lr = lane & 15, lk8 = (lane >> 4) * 8, r4 = (lane >> 4) * 4;
    const int scol = tid >> 1, sh = (tid & 1) * 16;

    {   // load x tile: 4 threads per row, 96 cols each
        const int xr = tid >> 2, xc = (tid & 3) * 96;
        const u16* xg = xq + (size_t)(row0 + xr) * 384 + xc;
        #pragma unroll
        for (int i = 0; i < 12; i++)
            *(uint4*)&Xs[xr][xc + i*8] = *(const uint4*)(xg + i*8);
    }
    __syncthreads();

    // ---- gate logits + softmax ----
    for (int task = tid; task < 512; task += 256){
        int r = task >> 3, e = task & 7;
        float s = gate_b[e];
        for (int k = 0; k < 384; k += 2){
            u32 u = *(const u32*)&Xs[r][k];
            s += bf2f((u16)(u & 0xFFFFu)) * gate_w[k*8 + e];
            s += bf2f((u16)(u >> 16))     * gate_w[(k+1)*8 + e];
        }
        GW[r][e] = s;
    }
    __syncthreads();
    if (tid < 64){
        float v[8], mx = -1e30f;
        #pragma unroll
        for (int e = 0; e < 8; e++){ v[e] = GW[tid][e]; mx = fmaxf(mx, v[e]); }
        float sum = 0.f;
        #pragma unroll
        for (int e = 0; e < 8; e++){ v[e] = __expf(v[e] - mx); sum += v[e]; }
        float inv = 1.f / sum;
        #pragma unroll
        for (int e = 0; e < 8; e++) GW[tid][e] = v[e] * inv;
    }
    // (GW consumed only after multiple barriers below)

    f32x4 fus[2][4];
    #pragma unroll
    for (int i = 0; i < 2; i++)
        #pragma unroll
        for (int j = 0; j < 4; j++) fus[i][j] = {0.f, 0.f, 0.f, 0.f};

    for (int e = 0; e < 8; e++){
        // ---- h = relu(x @ w1_e + b1) : [64x384]x[384x128] ----
        f32x4 acc[2][4];
        #pragma unroll
        for (int i = 0; i < 2; i++)
            #pragma unroll
            for (int j = 0; j < 4; j++) acc[i][j] = {0.f, 0.f, 0.f, 0.f};
        const u16* wg = w1T + (size_t)e*49152 + (size_t)scol*384 + sh;
        for (int kt = 0; kt < 384; kt += 32){
            __syncthreads();
            uint4 c0 = *(const uint4*)(wg + kt);
            uint4 c1 = *(const uint4*)(wg + kt + 8);
            *(uint4*)&Ws[scol][sh]     = c0;
            *(uint4*)&Ws[scol][sh + 8] = c1;
            __syncthreads();
            bf16x8 af[2], bfr[4];
            #pragma unroll
            for (int mi = 0; mi < 2; mi++) af[mi]  = *(const bf16x8*)&Xs[wr*32 + mi*16 + lr][kt + lk8];
            #pragma unroll
            for (int ni = 0; ni < 4; ni++) bfr[ni] = *(const bf16x8*)&Ws[wc*64 + ni*16 + lr][lk8];
            #pragma unroll
            for (int mi = 0; mi < 2; mi++)
                #pragma unroll
                for (int ni = 0; ni < 4; ni++)
                    acc[mi][ni] = __builtin_amdgcn_mfma_f32_16x16x32_bf16(af[mi], bfr[ni], acc[mi][ni], 0, 0, 0);
        }
        // write h (relu, bf16) — Hs reads of previous expert are barriers behind us
        #pragma unroll
        for (int mi = 0; mi < 2; mi++)
            #pragma unroll
            for (int ni = 0; ni < 4; ni++){
                int col = wc*64 + ni*16 + lr;
                float b1v = exp_b1[e*128 + col];
                #pragma unroll
                for (int j = 0; j < 4; j++){
                    int row = wr*32 + mi*16 + r4 + j;
                    Hs[row][col] = f2bf(fmaxf(acc[mi][ni][j] + b1v, 0.f));
                }
            }
        // ---- eo = h @ w2_e + b2 : [64x128]x[128x128] ----
        f32x4 acc2[2][4];
        #pragma unroll
        for (int i = 0; i < 2; i++)
            #pragma unroll
            for (int j = 0; j < 4; j++) acc2[i][j] = {0.f, 0.f, 0.f, 0.f};
        const u16* w2g = w2T + (size_t)e*16384 + (size_t)scol*128 + sh;
        for (int kt = 0; kt < 128; kt += 32){
            __syncthreads();   // also orders Hs writes before Hs reads
            uint4 c0 = *(const uint4*)(w2g + kt);
            uint4 c1 = *(const uint4*)(w2g + kt + 8);
            *(uint4*)&Ws[scol][sh]     = c0;
            *(uint4*)&Ws[scol][sh + 8] = c1;
            __syncthreads();
            bf16x8 af[2], bfr[4];
            #pragma unroll
            for (int mi = 0; mi < 2; mi++) af[mi]  = *(const bf16x8*)&Hs[wr*32 + mi*16 + lr][kt + lk8];
            #pragma unroll
            for (int ni = 0; ni < 4; ni++) bfr[ni] = *(const bf16x8*)&Ws[wc*64 + ni*16 + lr][lk8];
            #pragma unroll
            for (int mi = 0; mi < 2; mi++)
                #pragma unroll
                for (int ni = 0; ni < 4; ni++)
                    acc2[mi][ni] = __builtin_amdgcn_mfma_f32_16x16x32_bf16(af[mi], bfr[ni], acc2[mi][ni], 0, 0, 0);
        }
        // ---- fused += gw[:,e] * (eo + b2) ----
        #pragma unroll
        for (int mi = 0; mi < 2; mi++)
            #pragma unroll
            for (int ni = 0; ni < 4; ni++){
                int col = wc*64 + ni*16 + lr;
                float b2v = exp_b2[e*128 + col];
                #pragma unroll
                for (int j = 0; j < 4; j++){
                    int row = wr*32 + mi*16 + r4 + j;
                    fus[mi][ni][j] += GW[row][e] * (acc2[mi][ni][j] + b2v);
                }
            }
    }

    __syncthreads();  // all Hs reads (expert 7 w2) done before overwrite
    #pragma unroll
    for (int mi = 0; mi < 2; mi++)
        #pragma unroll
        for (int ni = 0; ni < 4; ni++)
            #pragma unroll
            for (int j = 0; j < 4; j++)
                Hs[wr*32 + mi*16 + r4 + j][wc*64 + ni*16 + lr] = f2bf(fus[mi][ni][j]);

    // ---- penult = relu(fused @ pre_w + pre_b) : [64x128]x[128x64] ----
    // waves 2x2 over 64x64 output: 32x32 per wave
    f32x4 accp[2][2];
    #pragma unroll
    for (int i = 0; i < 2; i++)
        #pragma unroll
        for (int j = 0; j < 2; j++) accp[i][j] = {0.f, 0.f, 0.f, 0.f};
    for (int kt = 0; kt < 128; kt += 32){
        __syncthreads();  // orders Hs(fused) writes before reads; protects Ws
        if (tid < 128){
            const u16* pg = prwT + (size_t)scol*128 + kt + sh;
            uint4 p0 = *(const uint4*)(pg);
            uint4 p1 = *(const uint4*)(pg + 8);
            *(uint4*)&Ws[scol][sh]     = p0;
            *(uint4*)&Ws[scol][sh + 8] = p1;
        }
        __syncthreads();
        bf16x8 af[2], bfr[2];
        #pragma unroll
        for (int mi = 0; mi < 2; mi++) af[mi]  = *(const bf16x8*)&Hs[wr*32 + mi*16 + lr][kt + lk8];
        #pragma unroll
        for (int ni = 0; ni < 2; ni++) bfr[ni] = *(const bf16x8*)&Ws[wc*32 + ni*16 + lr][lk8];
        #pragma unroll
        for (int mi = 0; mi < 2; mi++)
            #pragma unroll
            for (int ni = 0; ni < 2; ni++)
                accp[mi][ni] = __builtin_amdgcn_mfma_f32_16x16x32_bf16(af[mi], bfr[ni], accp[mi][ni], 0, 0, 0);
    }
    // penult (f32) into Xs region (x tile dead now)
    float* Pen = (float*)&Xs[0][0];   // [64][68]
    #pragma unroll
    for (int mi = 0; mi < 2; mi++)
        #pragma unroll
        for (int ni = 0; ni < 2; ni++){
            int col = wc*32 + ni*16 + lr;
            float pbv = pre_b[col];
            #pragma unroll
            for (int j = 0; j < 4; j++){
                int row = wr*32 + mi*16 + r4 + j;
                Pen[row*68 + col] = fmaxf(accp[mi][ni][j] + pbv, 0.f);
            }
        }
    __syncthreads();
    // ---- head ----
    if (tid < 128){
        int r = tid >> 1, c = tid & 1;
        float s = head_b[c];
        for (int k = 0; k < 64; k++) s += Pen[r*68 + k] * head_w[k*2 + c];
        out[(size_t)(row0 + r)*2 + c] = s;
    }
}

extern "C" void kernel_launch(void* const* d_in, const int* in_sizes, int n_in,
                              void* d_out, int out_size, void* d_ws, size_t ws_size,
                              hipStream_t stream) {
    const float* ft     = (const float*)d_in[0];
    const float* fa     = (const float*)d_in[1];
    const float* fv     = (const float*)d_in[2];
    const float* proj_w = (const float*)d_in[3];
    const float* proj_b = (const float*)d_in[4];
    const float* exp_w1 = (const float*)d_in[5];
    const float* exp_b1 = (const float*)d_in[6];
    const float* exp_w2 = (const float*)d_in[7];
    const float* exp_b2 = (const float*)d_in[8];
    const float* gate_w = (const float*)d_in[9];
    const float* gate_b = (const float*)d_in[10];
    const float* pre_w  = (const float*)d_in[11];
    const float* pre_b  = (const float*)d_in[12];
    const float* head_w = (const float*)d_in[13];
    const float* head_b = (const float*)d_in[14];
    float* out = (float*)d_out;

    u16* xq   = (u16*)d_ws;                       // 32768*384
    u16* pwT  = xq  + (size_t)B_ROWS * 384;       // 294912
    u16* w1T  = pwT + 294912;                     // 393216
    u16* w2T  = w1T + 393216;                     // 131072
    u16* prwT = w2T + 131072;                     // 8192

    cast_weights_kernel<<<3232, 256, 0, stream>>>(proj_w, exp_w1, exp_w2, pre_w,
                                                  pwT, w1T, w2T, prwT);
    proj_kernel<<<dim3(B_ROWS/128, 3), 256, 0, stream>>>(ft, fa, fv, pwT, proj_b, xq);
    moe_kernel<<<B_ROWS/64, 256, 0, stream>>>(xq, w1T, w2T, prwT,
                                              gate_w, gate_b, exp_b1, exp_b2,
                                              pre_b, head_w, head_b, out);
}